// Round 7
// baseline (232.007 us; speedup 1.0000x reference)
//
#include <hip/hip_runtime.h>
#include <cstddef>

#define T_STEPS 128
#define D_IN    57
#define HDIM    64
#define ODIM    7
#define FAN     121
#define GK      7296          // floats per x row == bf16 cols per G row (128*57)
#define KTOT    7239          // 127*57 real columns
#define GBYTES  ((size_t)HDIM * GK * 2)

typedef __attribute__((ext_vector_type(8))) short    short8;
typedef __attribute__((ext_vector_type(4))) float    f32x4;
typedef __attribute__((ext_vector_type(4))) unsigned uint4v;
typedef __attribute__((ext_vector_type(2))) unsigned uint2v;

#define MFMA(a,b,c) __builtin_amdgcn_mfma_f32_16x16x32_bf16((a),(b),(c),0,0,0)
#define DS_FENCE()  __builtin_amdgcn_sched_barrier(0x7F)

union FragU { short8 s8; unsigned u[4]; uint4v u4; };

__device__ inline unsigned short f2bf(float f) {
    __bf16 h = (__bf16)f;
    return __builtin_bit_cast(unsigned short, h);
}
__device__ inline float bf2f(unsigned short u) {
    return __builtin_bit_cast(float, (unsigned)u << 16);
}
__device__ inline unsigned pk2(float lo, float hi) {
    return ((unsigned)f2bf(hi) << 16) | (unsigned)f2bf(lo);
}

// A/B fragment builders (conventions HW-verified in rounds 3-6)
__device__ inline short8 wfragX(const float* Wr, int kbase) {
    FragU f;
#pragma unroll
    for (int d = 0; d < 4; ++d) {
        int k0 = kbase + 2 * d, k1 = k0 + 1;
        float a = (k0 < D_IN) ? Wr[k0] : 0.0f;
        float b = (k1 < D_IN) ? Wr[k1] : 0.0f;
        f.u[d] = pk2(a, b);
    }
    return f.s8;
}
__device__ inline short8 wfragH(const float* Wr, int kbase) {
    FragU f;
#pragma unroll
    for (int d = 0; d < 4; ++d) { int k0 = kbase + 2 * d; f.u[d] = pk2(Wr[k0], Wr[k0 + 1]); }
    return f.s8;
}
__device__ inline short8 xfrag(const float* r) {
    FragU f;
#pragma unroll
    for (int d = 0; d < 4; ++d) f.u[d] = pk2(r[2 * d], r[2 * d + 1]);
    return f.s8;
}

struct XR { float a[8]; float b[8]; };
__device__ inline void loadx(XR& r, const float* xrow, int t, int q) {
    const float* p = xrow + t * D_IN;
#pragma unroll
    for (int i = 0; i < 8; ++i) r.a[i] = p[q * 8 + i];
    if (q == 3) {
        r.b[0] = p[56];
#pragma unroll
        for (int i = 1; i < 8; ++i) r.b[i] = 0.0f;
    } else {
#pragma unroll
        for (int i = 0; i < 8; ++i) r.b[i] = p[32 + q * 8 + i];
    }
}

// ============ setup: build G[h][57t+c] = (W_h^(126-t) W_x)[h][c] (bf16) and Sb = sum W^j b ============
// Doubling: P_0 = W_x; given P_0..P_{k-1} and S_k = W_h^k: P_{k+j} = S_k P_j (MFMA, bf16);
// every n in 1..126 is uniquely n = k + j (k = 2^floor(log2 n)) -> each column block written once.
__global__ __launch_bounds__(1024) void rnn_scan_setup(
    const float* __restrict__ Wih, const float* __restrict__ bih, char* __restrict__ wsb)
{
    __shared__ float Sf[64][64];     // S_k fp32
    __shared__ float Vf[64][128];    // V_j = W^j b
    unsigned short* G = (unsigned short*)wsb;
    float* Sb = (float*)(wsb + GBYTES);
    const int tid = threadIdx.x;

    for (int i = tid; i < 4096; i += 1024) {
        int h = i >> 6, kk = i & 63;
        Sf[h][kk] = Wih[h * FAN + D_IN + kk];
    }
    for (int i = tid; i < 64 * 57; i += 1024) {
        int h = i / 57, c = i - h * 57;
        G[(size_t)h * GK + 57 * 126 + c] = f2bf(Wih[h * FAN + c]);  // P_0 = W_x (t=126)
        G[(size_t)h * GK + KTOT + c]     = 0;                       // pad [7239,7296)
    }
    if (tid < 64) Vf[tid][0] = bih[tid];
    __syncthreads();

    const int lane = tid & 63, wid = tid >> 6;
    const int st = lane & 15, q = lane >> 4;

    for (int k = 1; k <= 64; k <<= 1) {
        // A-frags of S_k (rows 16n+st, k-slots kb+2d(+1))
        short8 sa[4][2];
#pragma unroll
        for (int n = 0; n < 4; ++n)
#pragma unroll
            for (int hf = 0; hf < 2; ++hf) {
                FragU f;
                int kb = hf * 32 + 8 * q;
#pragma unroll
                for (int d = 0; d < 4; ++d)
                    f.u[d] = pk2(Sf[16 * n + st][kb + 2 * d], Sf[16 * n + st][kb + 2 * d + 1]);
                sa[n][hf] = f.s8;
            }
        // P-batch: waves share j's
        for (int j = wid; j < k; j += 16) {
            if (k + j > 126) break;
            const size_t csrc = (size_t)57 * (126 - j);
            const size_t cdst = (size_t)57 * (126 - (k + j));
#pragma unroll
            for (int m = 0; m < 4; ++m) {
                int cc = 16 * m + st;
                FragU b0, b1;
#pragma unroll
                for (int d = 0; d < 4; ++d) {
                    int k0 = 8 * q + 2 * d;
                    float e0 = 0, e1 = 0, e2 = 0, e3 = 0;
                    if (cc < 57) {
                        e0 = bf2f(G[(size_t)(k0    ) * GK + csrc + cc]);
                        e1 = bf2f(G[(size_t)(k0 + 1) * GK + csrc + cc]);
                        e2 = bf2f(G[(size_t)(k0 + 32) * GK + csrc + cc]);
                        e3 = bf2f(G[(size_t)(k0 + 33) * GK + csrc + cc]);
                    }
                    b0.u[d] = pk2(e0, e1);
                    b1.u[d] = pk2(e2, e3);
                }
#pragma unroll
                for (int n = 0; n < 4; ++n) {
                    f32x4 c = {0.f, 0.f, 0.f, 0.f};
                    c = MFMA(sa[n][0], b0.s8, c);
                    c = MFMA(sa[n][1], b1.s8, c);
                    if (cc < 57) {
#pragma unroll
                        for (int jj = 0; jj < 4; ++jj)
                            G[(size_t)(16 * n + 4 * q + jj) * GK + cdst + cc] = f2bf(c[jj]);
                    }
                }
            }
        }
        // V doubling (fp32): V_{k+j} = S_k V_j
        for (int idx = tid; idx < k * 64; idx += 1024) {
            int j = idx >> 6, h = idx & 63;
            if (k + j < 128) {
                float s = 0;
                for (int kk = 0; kk < 64; ++kk) s += Sf[h][kk] * Vf[kk][j];
                Vf[h][k + j] = s;
            }
        }
        // S squaring (fp32, into regs then writeback)
        float snew[4];
        if (k < 64) {
#pragma unroll
            for (int r = 0; r < 4; ++r) {
                int idx = tid + r * 1024;
                int h = idx >> 6, c = idx & 63;
                float s = 0;
                for (int kk = 0; kk < 64; ++kk) s += Sf[h][kk] * Sf[kk][c];
                snew[r] = s;
            }
        }
        __syncthreads();
        if (k < 64) {
#pragma unroll
            for (int r = 0; r < 4; ++r) {
                int idx = tid + r * 1024;
                Sf[idx >> 6][idx & 63] = snew[r];
            }
            __syncthreads();
        }
    }
    if (tid < 64) {
        float s = 0;
        for (int j = 0; j <= 126; ++j) s += Vf[tid][j];
        Sb[tid] = s;
    }
}

// ============ main: C[hid][seq] = G * x  (K = 7296, split over 8 waves), + epilogue ============
__global__ __launch_bounds__(512, 1) void rnn_scan_main(
    const float* __restrict__ x,
    const float* __restrict__ Wih,
    const float* __restrict__ bih,
    const float* __restrict__ Wio,
    const float* __restrict__ bio,
    const char*  __restrict__ wsb,
    float* __restrict__ out,
    int B)
{
    const unsigned short* G = (const unsigned short*)wsb;
    const float* Sb = (const float*)(wsb + GBYTES);
    const int tid  = threadIdx.x;
    const int wid  = tid >> 6, lane = tid & 63;
    const int st   = lane & 15, q = lane >> 4;
    const int seq0 = blockIdx.x * 16;

    __shared__ float Red[8][1024];
    __shared__ float Hp[16][68];
    __shared__ float Lg[16][8];
    __shared__ int   Tl[16];
    __shared__ unsigned char Mb[16][32];
    __shared__ unsigned Mm[16][4];

    const bool fullblk = (seq0 + 16 <= B);
    int seqc = seq0 + st; if (seqc >= B) seqc = B - 1;
    const float* xs = x + (size_t)seqc * GK;

    // validity masks: 512 threads x 4 t each
    {
        int s = tid & 15, g = tid >> 4;
        int sc = seq0 + s; if (sc >= B) sc = B - 1;
        const float* xr = x + (size_t)sc * GK;
        unsigned v = 0;
#pragma unroll
        for (int i = 0; i < 4; ++i)
            v |= ((xr[(size_t)(4 * g + i) * D_IN] != -1.0f) ? 1u : 0u) << i;
        Mb[s][g] = (unsigned char)v;
    }
    __syncthreads();
    int myAllv = 1;
    if (tid < 16) {
        unsigned mk[4] = {0, 0, 0, 0};
        for (int b = 0; b < 32; ++b)
            mk[b >> 3] |= ((unsigned)Mb[tid][b]) << ((b & 7) * 4);
        Mm[tid][0] = mk[0]; Mm[tid][1] = mk[1]; Mm[tid][2] = mk[2]; Mm[tid][3] = mk[3];
        myAllv = ((mk[0] & mk[1] & mk[2] & mk[3]) == 0xFFFFFFFFu) ? 1 : 0;
        int tl;
        if (mk[3])      tl = 127 - __builtin_clz(mk[3]);
        else if (mk[2]) tl =  95 - __builtin_clz(mk[2]);
        else if (mk[1]) tl =  63 - __builtin_clz(mk[1]);
        else if (mk[0]) tl =  31 - __builtin_clz(mk[0]);
        else            tl = -1;
        Tl[tid] = tl;
    }
    const int blockFast = __syncthreads_and(myAllv) && fullblk;

    // ---- K-loop: wave wid covers its K segment in chunks of 32 ----
    int nch, kw;
    if (wid < 4) { nch = 29; kw = 928 * wid; }
    else         { nch = 28; kw = 3712 + 896 * (wid - 4); }

    f32x4 acc0 = {0,0,0,0}, acc1 = {0,0,0,0}, acc2 = {0,0,0,0}, acc3 = {0,0,0,0};
    const unsigned short* g0 = G + (size_t)(st)      * GK;
    const unsigned short* g1 = G + (size_t)(16 + st) * GK;
    const unsigned short* g2 = G + (size_t)(32 + st) * GK;
    const unsigned short* g3 = G + (size_t)(48 + st) * GK;

#pragma unroll 2
    for (int c = 0; c < nch; ++c) {
        int k0 = kw + 32 * c + 8 * q;
        f32x4 xa = *(const f32x4*)(xs + k0);
        f32x4 xb = *(const f32x4*)(xs + k0 + 4);
        FragU bx;
        bx.u[0] = pk2(xa[0], xa[1]); bx.u[1] = pk2(xa[2], xa[3]);
        bx.u[2] = pk2(xb[0], xb[1]); bx.u[3] = pk2(xb[2], xb[3]);
        FragU a0, a1, a2, a3;
        a0.u4 = *(const uint4v*)(g0 + k0);
        a1.u4 = *(const uint4v*)(g1 + k0);
        a2.u4 = *(const uint4v*)(g2 + k0);
        a3.u4 = *(const uint4v*)(g3 + k0);
        acc0 = MFMA(a0.s8, bx.s8, acc0);
        acc1 = MFMA(a1.s8, bx.s8, acc1);
        acc2 = MFMA(a2.s8, bx.s8, acc2);
        acc3 = MFMA(a3.s8, bx.s8, acc3);
    }
    {
        const f32x4 av[4] = { acc0, acc1, acc2, acc3 };
#pragma unroll
        for (int n = 0; n < 4; ++n)
#pragma unroll
            for (int jj = 0; jj < 4; ++jj)
                Red[wid][(16 * n + 4 * q + jj) * 16 + st] = av[n][jj];
    }
    __syncthreads();
    for (int idx = tid; idx < 1024; idx += 512) {
        float s = 0;
#pragma unroll
        for (int w = 0; w < 8; ++w) s += Red[w][idx];
        int hid = idx >> 4, sq = idx & 15;
        Hp[sq][hid] = s + Sb[hid];
    }
    __syncthreads();

    // ---- fallback: any invalid timestep (or partial block) -> sequential recurrence (wave 0) ----
    if (!blockFast) {
        if (wid == 0) {
            unsigned short* HsS = (unsigned short*)&Red[0][0];   // reuse (Red consumed)
            char* HsB = (char*)HsS;
            { uint4v z = {0,0,0,0};
              *(uint4v*)(HsB + lane * 32) = z; *(uint4v*)(HsB + lane * 32 + 16) = z; }
            short8 wxf[4][2], whf[4][2]; f32x4 biasv[4];
#pragma unroll
            for (int n = 0; n < 4; ++n) {
                const float* wr_ = Wih + (size_t)(16 * n + st) * FAN;
                wxf[n][0] = wfragX(wr_, q * 8);
                wxf[n][1] = wfragX(wr_, 32 + q * 8);
                whf[n][0] = wfragH(wr_ + D_IN, q * 8);
                whf[n][1] = wfragH(wr_ + D_IN, 32 + q * 8);
#pragma unroll
                for (int jj = 0; jj < 4; ++jj) biasv[n][jj] = bih[16 * n + 4 * q + jj];
            }
            const unsigned rb0 = (unsigned)(128 * st + 16 * q);
            const unsigned rb1 = (unsigned)(128 * st + 64 + 16 * q);
            unsigned wb[4];
#pragma unroll
            for (int n = 0; n < 4; ++n) wb[n] = (unsigned)(128 * st + 32 * n + 8 * q);
            unsigned mkw[4] = { Mm[st][0], Mm[st][1], Mm[st][2], Mm[st][3] };
            f32x4 hcur[4], hpre[4];
#pragma unroll
            for (int n = 0; n < 4; ++n) { hcur[n] = (f32x4){0,0,0,0}; hpre[n] = (f32x4){0,0,0,0}; }
#pragma unroll 1
            for (int t = 0; t < T_STEPS; ++t) {
                XR r; loadx(r, xs, t, q);
                FragU bh0, bh1;
                bh0.u4 = *(const uint4v*)(HsB + rb0);
                bh1.u4 = *(const uint4v*)(HsB + rb1);
                short8 bx0 = xfrag(r.a), bx1 = xfrag(r.b);
                f32x4 acc[4];
#pragma unroll
                for (int n = 0; n < 4; ++n) {
                    f32x4 cc2 = biasv[n];
                    cc2 = MFMA(wxf[n][0], bx0, cc2);
                    cc2 = MFMA(wxf[n][1], bx1, cc2);
                    cc2 = MFMA(whf[n][0], bh0.s8, cc2);
                    cc2 = MFMA(whf[n][1], bh1.s8, cc2);
                    acc[n] = cc2;
                }
                bool v = ((mkw[t >> 5] >> (t & 31)) & 1u) != 0;
#pragma unroll
                for (int n = 0; n < 4; ++n)
#pragma unroll
                    for (int jj = 0; jj < 4; ++jj) {
                        float o = hcur[n][jj];
                        hpre[n][jj] = v ? o : hpre[n][jj];
                        hcur[n][jj] = v ? acc[n][jj] : o;
                    }
#pragma unroll
                for (int n = 0; n < 4; ++n) {
                    uint2v w2;
                    w2[0] = pk2(hcur[n][0], hcur[n][1]);
                    w2[1] = pk2(hcur[n][2], hcur[n][3]);
                    *(uint2v*)(HsB + wb[n]) = w2;
                }
                DS_FENCE();
            }
#pragma unroll
            for (int n = 0; n < 4; ++n)
                *(f32x4*)&Hp[st][16 * n + 4 * q] = hpre[n];
        }
        __syncthreads();
    }

    // ---- output projection + log_softmax ----
    if (tid < 64) {
        int s = tid >> 2, p = tid & 3;
        int seq = seq0 + s;
        int t_l = Tl[s];
        float lgo0 = 0.0f, lgo1 = 0.0f;
        if (seq < B && t_l >= 0) {
            const float* xr = x + (size_t)seq * GK + (size_t)t_l * D_IN;
            {
                const float* wo = Wio + p * FAN;
                float a = bio[p];
                for (int k = 0; k < D_IN; ++k) a += xr[k] * wo[k];
                for (int k = 0; k < HDIM; ++k) a += Hp[s][k] * wo[D_IN + k];
                lgo0 = a;
            }
            if (p < 3) {
                const float* wo = Wio + (p + 4) * FAN;
                float a = bio[p + 4];
                for (int k = 0; k < D_IN; ++k) a += xr[k] * wo[k];
                for (int k = 0; k < HDIM; ++k) a += Hp[s][k] * wo[D_IN + k];
                lgo1 = a;
            }
        }
        Lg[s][p] = lgo0;
        if (p < 3) Lg[s][p + 4] = lgo1;
    }
    __syncthreads();
    if (tid < 16) {
        int s = tid, seq = seq0 + s;
        if (seq < B) {
            float* op = out + (size_t)seq * ODIM;
            if (Tl[s] < 0) {
#pragma unroll
                for (int o = 0; o < ODIM; ++o) op[o] = 0.0f;
            } else {
                float m = Lg[s][0];
#pragma unroll
                for (int o = 1; o < ODIM; ++o) m = fmaxf(m, Lg[s][o]);
                float sum = 0.0f;
#pragma unroll
                for (int o = 0; o < ODIM; ++o) sum += expf(Lg[s][o] - m);
                float lse = m + logf(sum);
#pragma unroll
                for (int o = 0; o < ODIM; ++o) op[o] = Lg[s][o] - lse;
            }
        }
    }
}

extern "C" void kernel_launch(void* const* d_in, const int* in_sizes, int n_in,
                              void* d_out, int out_size, void* d_ws, size_t ws_size,
                              hipStream_t stream)
{
    const float* x     = (const float*)d_in[0];
    const float* W_i2h = (const float*)d_in[1];
    const float* b_i2h = (const float*)d_in[2];
    const float* W_i2o = (const float*)d_in[3];
    const float* b_i2o = (const float*)d_in[4];
    float* out = (float*)d_out;
    char*  wsb = (char*)d_ws;

    const int B = in_sizes[0] / (T_STEPS * D_IN);
    const int nblk = (B + 15) / 16;

    hipLaunchKernelGGL(rnn_scan_setup, dim3(1), dim3(1024), 0, stream, W_i2h, b_i2h, wsb);
    hipLaunchKernelGGL(rnn_scan_main, dim3(nblk), dim3(512), 0, stream,
                       x, W_i2h, b_i2h, W_i2o, b_i2o, (const char*)wsb, out, B);
}

// Round 8
// 200.029 us; speedup vs baseline: 1.1599x; 1.1599x over previous
//
#include <hip/hip_runtime.h>
#include <cstddef>

#define T_STEPS 128
#define D_IN    57
#define HDIM    64
#define ODIM    7
#define FAN     121
#define GK      7296          // floats per x row == bf16 cols per G row (128*57)
#define KTOT    7239          // 127*57 real columns
#define GBYTES  ((size_t)HDIM * GK * 2)
#define POW_OFF (GBYTES + 256)

typedef __attribute__((ext_vector_type(8))) short    short8;
typedef __attribute__((ext_vector_type(4))) float    f32x4;
typedef __attribute__((ext_vector_type(4))) unsigned uint4v;
typedef __attribute__((ext_vector_type(2))) unsigned uint2v;

#define MFMA(a,b,c) __builtin_amdgcn_mfma_f32_16x16x32_bf16((a),(b),(c),0,0,0)
#define DS_FENCE()  __builtin_amdgcn_sched_barrier(0x7F)

union FragU { short8 s8; unsigned u[4]; uint4v u4; };

__device__ inline unsigned short f2bf(float f) {
    __bf16 h = (__bf16)f;
    return __builtin_bit_cast(unsigned short, h);
}
__device__ inline float bf2f(unsigned short u) {
    return __builtin_bit_cast(float, (unsigned)u << 16);
}
__device__ inline unsigned pk2(float lo, float hi) {
    return ((unsigned)f2bf(hi) << 16) | (unsigned)f2bf(lo);
}

__device__ inline short8 wfragX(const float* Wr, int kbase) {
    FragU f;
#pragma unroll
    for (int d = 0; d < 4; ++d) {
        int k0 = kbase + 2 * d, k1 = k0 + 1;
        float a = (k0 < D_IN) ? Wr[k0] : 0.0f;
        float b = (k1 < D_IN) ? Wr[k1] : 0.0f;
        f.u[d] = pk2(a, b);
    }
    return f.s8;
}
__device__ inline short8 wfragH(const float* Wr, int kbase) {
    FragU f;
#pragma unroll
    for (int d = 0; d < 4; ++d) { int k0 = kbase + 2 * d; f.u[d] = pk2(Wr[k0], Wr[k0 + 1]); }
    return f.s8;
}
__device__ inline short8 xfrag(const float* r) {
    FragU f;
#pragma unroll
    for (int d = 0; d < 4; ++d) f.u[d] = pk2(r[2 * d], r[2 * d + 1]);
    return f.s8;
}

struct XR { float a[8]; float b[8]; };
__device__ inline void loadx(XR& r, const float* xrow, int t, int q) {
    const float* p = xrow + t * D_IN;
#pragma unroll
    for (int i = 0; i < 8; ++i) r.a[i] = p[q * 8 + i];
    if (q == 3) {
        r.b[0] = p[56];
#pragma unroll
        for (int i = 1; i < 8; ++i) r.b[i] = 0.0f;
    } else {
#pragma unroll
        for (int i = 0; i < 8; ++i) r.b[i] = p[32 + q * 8 + i];
    }
}

// ===== setup A (1 block): powers W^(2^i) i=0..6 (bf16 -> ws), Sb = sum_{j<=126} W^j b, G pad zero =====
__global__ __launch_bounds__(1024) void rnn_scan_setup(
    const float* __restrict__ Wih, const float* __restrict__ bih, char* __restrict__ wsb)
{
    __shared__ float Sf[64][64];     // current power (fp32)
    __shared__ float Vf[64][128];    // V_j = W^j b
    unsigned short* G   = (unsigned short*)wsb;
    float*          Sb  = (float*)(wsb + GBYTES);
    unsigned short* POW = (unsigned short*)(wsb + POW_OFF);
    const int tid = threadIdx.x;

    for (int i = tid; i < 4096; i += 1024) {
        int h = i >> 6, kk = i & 63;
        Sf[h][kk] = Wih[h * FAN + D_IN + kk];
    }
    for (int i = tid; i < 64 * (GK - KTOT); i += 1024) {
        int h = i / (GK - KTOT), c = i % (GK - KTOT);
        G[(size_t)h * GK + KTOT + c] = 0;
    }
    if (tid < 64) Vf[tid][0] = bih[tid];
    __syncthreads();

    for (int i = tid; i < 4096; i += 1024)        // pow_0 = W
        POW[i] = f2bf(Sf[i >> 6][i & 63]);

    int pi = 1;
    for (int k = 1; k <= 64; k <<= 1) {
        // V doubling: V_{k+j} = W^k V_j (reads j<k, writes >=k -> disjoint)
        for (int idx = tid; idx < k * 64; idx += 1024) {
            int j = idx >> 6, h = idx & 63;
            if (k + j < 128) {
                float s = 0;
                for (int kk = 0; kk < 64; ++kk) s += Sf[h][kk] * Vf[kk][j];
                Vf[h][k + j] = s;
            }
        }
        if (k < 64) {
            float snew[4];
#pragma unroll
            for (int r = 0; r < 4; ++r) {
                int idx = tid + r * 1024;
                int h = idx >> 6, c = idx & 63;
                float s = 0;
                for (int kk = 0; kk < 64; ++kk) s += Sf[h][kk] * Sf[kk][c];
                snew[r] = s;
            }
            __syncthreads();
#pragma unroll
            for (int r = 0; r < 4; ++r) {
                int idx = tid + r * 1024;
                Sf[idx >> 6][idx & 63] = snew[r];
            }
            __syncthreads();
            for (int i = tid; i < 4096; i += 1024)
                POW[pi * 4096 + i] = f2bf(Sf[i >> 6][i & 63]);
            ++pi;
        }
    }
    __syncthreads();   // all Vf writes visible before the sum (fixes R7 race)
    if (tid < 64) {
        float s = 0;
        for (int j = 0; j <= 126; ++j) s += Vf[tid][j];
        Sb[tid] = s;
    }
}

// ===== setup B (127 blocks): G_t = W^(126-t) * Wx via binary power chain, fp32 in LDS =====
__global__ __launch_bounds__(512) void rnn_scan_powapply(
    const float* __restrict__ Wih, char* __restrict__ wsb)
{
    unsigned short*       G   = (unsigned short*)wsb;
    const unsigned short* POW = (const unsigned short*)(wsb + POW_OFF);
    const int t   = blockIdx.x;       // 0..126
    const int n   = 126 - t;
    const int tid = threadIdx.x;

    __shared__ float Pa[64][64], Pb[64][64];
    __shared__ float Pw[64][65];      // padded: breaks stride-64 bank aliasing

    for (int i = tid; i < 64 * 64; i += 512) {
        int h = i >> 6, c = i & 63;
        Pa[h][c] = (c < D_IN) ? Wih[h * FAN + c] : 0.0f;
    }
    __syncthreads();

    float (*src)[64] = Pa;
    float (*dst)[64] = Pb;
    const int h  = tid >> 3;
    const int c0 = (tid & 7) * 8;

    for (int i = 6; i >= 0; --i) {
        if (!((n >> i) & 1)) continue;
        for (int e = tid; e < 4096; e += 512)
            Pw[e >> 6][e & 63] = bf2f(POW[(size_t)i * 4096 + e]);
        __syncthreads();
        float acc[8];
#pragma unroll
        for (int j = 0; j < 8; ++j) acc[j] = 0.0f;
        for (int k = 0; k < 64; ++k) {
            float p = Pw[h][k];
#pragma unroll
            for (int j = 0; j < 8; ++j) acc[j] += p * src[k][c0 + j];
        }
        __syncthreads();
#pragma unroll
        for (int j = 0; j < 8; ++j) dst[h][c0 + j] = acc[j];
        __syncthreads();
        float (*tmp)[64] = src; src = dst; dst = tmp;
    }

    for (int i = tid; i < 64 * D_IN; i += 512) {
        int h2 = i / D_IN, c = i - h2 * D_IN;
        G[(size_t)h2 * GK + 57 * t + c] = f2bf(src[h2][c]);
    }
}

// ===== main: C[hid][seq] = G * x  (K = 7296, 8 waves), + epilogue (unchanged from R7) =====
__global__ __launch_bounds__(512, 1) void rnn_scan_main(
    const float* __restrict__ x,
    const float* __restrict__ Wih,
    const float* __restrict__ bih,
    const float* __restrict__ Wio,
    const float* __restrict__ bio,
    const char*  __restrict__ wsb,
    float* __restrict__ out,
    int B)
{
    const unsigned short* G = (const unsigned short*)wsb;
    const float* Sb = (const float*)(wsb + GBYTES);
    const int tid  = threadIdx.x;
    const int wid  = tid >> 6, lane = tid & 63;
    const int st   = lane & 15, q = lane >> 4;
    const int seq0 = blockIdx.x * 16;

    __shared__ float Red[8][1024];
    __shared__ float Hp[16][68];
    __shared__ float Lg[16][8];
    __shared__ int   Tl[16];
    __shared__ unsigned char Mb[16][32];
    __shared__ unsigned Mm[16][4];

    const bool fullblk = (seq0 + 16 <= B);
    int seqc = seq0 + st; if (seqc >= B) seqc = B - 1;
    const float* xs = x + (size_t)seqc * GK;

    {
        int s = tid & 15, g = tid >> 4;
        int sc = seq0 + s; if (sc >= B) sc = B - 1;
        const float* xr = x + (size_t)sc * GK;
        unsigned v = 0;
#pragma unroll
        for (int i = 0; i < 4; ++i)
            v |= ((xr[(size_t)(4 * g + i) * D_IN] != -1.0f) ? 1u : 0u) << i;
        Mb[s][g] = (unsigned char)v;
    }
    __syncthreads();
    int myAllv = 1;
    if (tid < 16) {
        unsigned mk[4] = {0, 0, 0, 0};
        for (int b = 0; b < 32; ++b)
            mk[b >> 3] |= ((unsigned)Mb[tid][b]) << ((b & 7) * 4);
        Mm[tid][0] = mk[0]; Mm[tid][1] = mk[1]; Mm[tid][2] = mk[2]; Mm[tid][3] = mk[3];
        myAllv = ((mk[0] & mk[1] & mk[2] & mk[3]) == 0xFFFFFFFFu) ? 1 : 0;
        int tl;
        if (mk[3])      tl = 127 - __builtin_clz(mk[3]);
        else if (mk[2]) tl =  95 - __builtin_clz(mk[2]);
        else if (mk[1]) tl =  63 - __builtin_clz(mk[1]);
        else if (mk[0]) tl =  31 - __builtin_clz(mk[0]);
        else            tl = -1;
        Tl[tid] = tl;
    }
    const int blockFast = __syncthreads_and(myAllv) && fullblk;

    int nch, kw;
    if (wid < 4) { nch = 29; kw = 928 * wid; }
    else         { nch = 28; kw = 3712 + 896 * (wid - 4); }

    f32x4 acc0 = {0,0,0,0}, acc1 = {0,0,0,0}, acc2 = {0,0,0,0}, acc3 = {0,0,0,0};
    const unsigned short* g0 = G + (size_t)(st)      * GK;
    const unsigned short* g1 = G + (size_t)(16 + st) * GK;
    const unsigned short* g2 = G + (size_t)(32 + st) * GK;
    const unsigned short* g3 = G + (size_t)(48 + st) * GK;

#pragma unroll 2
    for (int c = 0; c < nch; ++c) {
        int k0 = kw + 32 * c + 8 * q;
        f32x4 xa = *(const f32x4*)(xs + k0);
        f32x4 xb = *(const f32x4*)(xs + k0 + 4);
        FragU bx;
        bx.u[0] = pk2(xa[0], xa[1]); bx.u[1] = pk2(xa[2], xa[3]);
        bx.u[2] = pk2(xb[0], xb[1]); bx.u[3] = pk2(xb[2], xb[3]);
        FragU a0, a1, a2, a3;
        a0.u4 = *(const uint4v*)(g0 + k0);
        a1.u4 = *(const uint4v*)(g1 + k0);
        a2.u4 = *(const uint4v*)(g2 + k0);
        a3.u4 = *(const uint4v*)(g3 + k0);
        acc0 = MFMA(a0.s8, bx.s8, acc0);
        acc1 = MFMA(a1.s8, bx.s8, acc1);
        acc2 = MFMA(a2.s8, bx.s8, acc2);
        acc3 = MFMA(a3.s8, bx.s8, acc3);
    }
    {
        const f32x4 av[4] = { acc0, acc1, acc2, acc3 };
#pragma unroll
        for (int n = 0; n < 4; ++n)
#pragma unroll
            for (int jj = 0; jj < 4; ++jj)
                Red[wid][(16 * n + 4 * q + jj) * 16 + st] = av[n][jj];
    }
    __syncthreads();
    for (int idx = tid; idx < 1024; idx += 512) {
        float s = 0;
#pragma unroll
        for (int w = 0; w < 8; ++w) s += Red[w][idx];
        int hid = idx >> 4, sq = idx & 15;
        Hp[sq][hid] = s + Sb[hid];
    }
    __syncthreads();

    if (!blockFast) {
        if (wid == 0) {
            unsigned short* HsS = (unsigned short*)&Red[0][0];
            char* HsB = (char*)HsS;
            { uint4v z = {0,0,0,0};
              *(uint4v*)(HsB + lane * 32) = z; *(uint4v*)(HsB + lane * 32 + 16) = z; }
            short8 wxf[4][2], whf[4][2]; f32x4 biasv[4];
#pragma unroll
            for (int n = 0; n < 4; ++n) {
                const float* wr_ = Wih + (size_t)(16 * n + st) * FAN;
                wxf[n][0] = wfragX(wr_, q * 8);
                wxf[n][1] = wfragX(wr_, 32 + q * 8);
                whf[n][0] = wfragH(wr_ + D_IN, q * 8);
                whf[n][1] = wfragH(wr_ + D_IN, 32 + q * 8);
#pragma unroll
                for (int jj = 0; jj < 4; ++jj) biasv[n][jj] = bih[16 * n + 4 * q + jj];
            }
            const unsigned rb0 = (unsigned)(128 * st + 16 * q);
            const unsigned rb1 = (unsigned)(128 * st + 64 + 16 * q);
            unsigned wb[4];
#pragma unroll
            for (int n = 0; n < 4; ++n) wb[n] = (unsigned)(128 * st + 32 * n + 8 * q);
            unsigned mkw[4] = { Mm[st][0], Mm[st][1], Mm[st][2], Mm[st][3] };
            f32x4 hcur[4], hpre[4];
#pragma unroll
            for (int n = 0; n < 4; ++n) { hcur[n] = (f32x4){0,0,0,0}; hpre[n] = (f32x4){0,0,0,0}; }
#pragma unroll 1
            for (int t = 0; t < T_STEPS; ++t) {
                XR r; loadx(r, xs, t, q);
                FragU bh0, bh1;
                bh0.u4 = *(const uint4v*)(HsB + rb0);
                bh1.u4 = *(const uint4v*)(HsB + rb1);
                short8 bx0 = xfrag(r.a), bx1 = xfrag(r.b);
                f32x4 acc[4];
#pragma unroll
                for (int n = 0; n < 4; ++n) {
                    f32x4 cc2 = biasv[n];
                    cc2 = MFMA(wxf[n][0], bx0, cc2);
                    cc2 = MFMA(wxf[n][1], bx1, cc2);
                    cc2 = MFMA(whf[n][0], bh0.s8, cc2);
                    cc2 = MFMA(whf[n][1], bh1.s8, cc2);
                    acc[n] = cc2;
                }
                bool v = ((mkw[t >> 5] >> (t & 31)) & 1u) != 0;
#pragma unroll
                for (int n = 0; n < 4; ++n)
#pragma unroll
                    for (int jj = 0; jj < 4; ++jj) {
                        float o = hcur[n][jj];
                        hpre[n][jj] = v ? o : hpre[n][jj];
                        hcur[n][jj] = v ? acc[n][jj] : o;
                    }
#pragma unroll
                for (int n = 0; n < 4; ++n) {
                    uint2v w2;
                    w2[0] = pk2(hcur[n][0], hcur[n][1]);
                    w2[1] = pk2(hcur[n][2], hcur[n][3]);
                    *(uint2v*)(HsB + wb[n]) = w2;
                }
                DS_FENCE();
            }
#pragma unroll
            for (int n = 0; n < 4; ++n)
                *(f32x4*)&Hp[st][16 * n + 4 * q] = hpre[n];
        }
        __syncthreads();
    }

    if (tid < 64) {
        int s = tid >> 2, p = tid & 3;
        int seq = seq0 + s;
        int t_l = Tl[s];
        float lgo0 = 0.0f, lgo1 = 0.0f;
        if (seq < B && t_l >= 0) {
            const float* xr = x + (size_t)seq * GK + (size_t)t_l * D_IN;
            {
                const float* wo = Wio + p * FAN;
                float a = bio[p];
                for (int k = 0; k < D_IN; ++k) a += xr[k] * wo[k];
                for (int k = 0; k < HDIM; ++k) a += Hp[s][k] * wo[D_IN + k];
                lgo0 = a;
            }
            if (p < 3) {
                const float* wo = Wio + (p + 4) * FAN;
                float a = bio[p + 4];
                for (int k = 0; k < D_IN; ++k) a += xr[k] * wo[k];
                for (int k = 0; k < HDIM; ++k) a += Hp[s][k] * wo[D_IN + k];
                lgo1 = a;
            }
        }
        Lg[s][p] = lgo0;
        if (p < 3) Lg[s][p + 4] = lgo1;
    }
    __syncthreads();
    if (tid < 16) {
        int s = tid, seq = seq0 + s;
        if (seq < B) {
            float* op = out + (size_t)seq * ODIM;
            if (Tl[s] < 0) {
#pragma unroll
                for (int o = 0; o < ODIM; ++o) op[o] = 0.0f;
            } else {
                float m = Lg[s][0];
#pragma unroll
                for (int o = 1; o < ODIM; ++o) m = fmaxf(m, Lg[s][o]);
                float sum = 0.0f;
#pragma unroll
                for (int o = 0; o < ODIM; ++o) sum += expf(Lg[s][o] - m);
                float lse = m + logf(sum);
#pragma unroll
                for (int o = 0; o < ODIM; ++o) op[o] = Lg[s][o] - lse;
            }
        }
    }
}

extern "C" void kernel_launch(void* const* d_in, const int* in_sizes, int n_in,
                              void* d_out, int out_size, void* d_ws, size_t ws_size,
                              hipStream_t stream)
{
    const float* x     = (const float*)d_in[0];
    const float* W_i2h = (const float*)d_in[1];
    const float* b_i2h = (const float*)d_in[2];
    const float* W_i2o = (const float*)d_in[3];
    const float* b_i2o = (const float*)d_in[4];
    float* out = (float*)d_out;
    char*  wsb = (char*)d_ws;

    const int B = in_sizes[0] / (T_STEPS * D_IN);
    const int nblk = (B + 15) / 16;

    hipLaunchKernelGGL(rnn_scan_setup,    dim3(1),    dim3(1024), 0, stream, W_i2h, b_i2h, wsb);
    hipLaunchKernelGGL(rnn_scan_powapply, dim3(127),  dim3(512),  0, stream, W_i2h, wsb);
    hipLaunchKernelGGL(rnn_scan_main,     dim3(nblk), dim3(512),  0, stream,
                       x, W_i2h, b_i2h, W_i2o, b_i2o, (const char*)wsb, out, B);
}

// Round 9
// 65.422 us; speedup vs baseline: 3.5463x; 3.0575x over previous
//
#include <hip/hip_runtime.h>
#include <cstddef>

#define T_STEPS 128
#define D_IN    57
#define HDIM    64
#define ODIM    7
#define FAN     121
#define GK      7296          // floats per x row == bf16 cols per G row (128*57)
#define KTOT    7239          // 127*57 real columns
#define GBYTES  ((size_t)HDIM * GK * 2)

typedef __attribute__((ext_vector_type(8))) short    short8;
typedef __attribute__((ext_vector_type(4))) float    f32x4;
typedef __attribute__((ext_vector_type(4))) unsigned uint4v;
typedef __attribute__((ext_vector_type(2))) unsigned uint2v;

#define MFMA(a,b,c) __builtin_amdgcn_mfma_f32_16x16x32_bf16((a),(b),(c),0,0,0)
#define DS_FENCE()  __builtin_amdgcn_sched_barrier(0x7F)

union FragU { short8 s8; unsigned u[4]; uint4v u4; };

__device__ inline unsigned short f2bf(float f) {
    __bf16 h = (__bf16)f;
    return __builtin_bit_cast(unsigned short, h);
}
__device__ inline float bf2f(unsigned short u) {
    return __builtin_bit_cast(float, (unsigned)u << 16);
}
__device__ inline unsigned pk2(float lo, float hi) {
    return ((unsigned)f2bf(hi) << 16) | (unsigned)f2bf(lo);
}
// Involutive swizzle for 128B-row LDS tiles (verified R3-R6)
__device__ inline unsigned swz(unsigned b) {
    return b ^ (((b >> 7) & 7u) << 4);
}

__device__ inline short8 wfragX(const float* Wr, int kbase) {
    FragU f;
#pragma unroll
    for (int d = 0; d < 4; ++d) {
        int k0 = kbase + 2 * d, k1 = k0 + 1;
        float a = (k0 < D_IN) ? Wr[k0] : 0.0f;
        float b = (k1 < D_IN) ? Wr[k1] : 0.0f;
        f.u[d] = pk2(a, b);
    }
    return f.s8;
}
__device__ inline short8 wfragH(const float* Wr, int kbase) {
    FragU f;
#pragma unroll
    for (int d = 0; d < 4; ++d) { int k0 = kbase + 2 * d; f.u[d] = pk2(Wr[k0], Wr[k0 + 1]); }
    return f.s8;
}
__device__ inline short8 xfrag(const float* r) {
    FragU f;
#pragma unroll
    for (int d = 0; d < 4; ++d) f.u[d] = pk2(r[2 * d], r[2 * d + 1]);
    return f.s8;
}

struct XR { float a[8]; float b[8]; };
__device__ inline void loadx(XR& r, const float* xrow, int t, int q) {
    const float* p = xrow + t * D_IN;
#pragma unroll
    for (int i = 0; i < 8; ++i) r.a[i] = p[q * 8 + i];
    if (q == 3) {
        r.b[0] = p[56];
#pragma unroll
        for (int i = 1; i < 8; ++i) r.b[i] = 0.0f;
    } else {
#pragma unroll
        for (int i = 0; i < 8; ++i) r.b[i] = p[32 + q * 8 + i];
    }
}

// ===== prep (128 blocks, fully parallel, MFMA in swizzled bf16 LDS) =====
// Block t<127: G_t = W_h^(126-t) * W_x  (redundant per-block squaring chain, <=12 matmuls)
// Block 127:   Sb = sum_{j<=126} W_h^j b  (u/w doubling recursions) + zero-pad G tail
__global__ __launch_bounds__(512, 1) void rnn_prep(
    const float* __restrict__ Wih, const float* __restrict__ bih, char* __restrict__ wsb)
{
    unsigned short* G  = (unsigned short*)wsb;
    float*          Sb = (float*)(wsb + GBYTES);
    const int t    = blockIdx.x;          // 0..127
    const int n    = 126 - t;             // t==127 -> n<0: no cur-mults
    const int tid  = threadIdx.x;
    const int lane = tid & 63, wid = tid >> 6;
    const int st   = lane & 15, q = lane >> 4;

    __shared__ __align__(16) unsigned short Arow[2][64][64];  // S_i row-major (k-packed)
    __shared__ __align__(16) unsigned short Acol[2][64][64];  // S_i col-major: Acol[c][k]=S[k][c]
    __shared__ __align__(16) unsigned short Ccol[2][64][64];  // cur col-major
    __shared__ float Ub[64], Wb[64], Ptu[64][8], Ptw[64][8];

    // init: Arow/Acol = W_h; Ccol = W_x (cols>=57 zero)
    {
        const int h  = tid & 63;
        const int k0 = (tid >> 6) * 8;
        unsigned ur[4], uc[4], ux[4];
#pragma unroll
        for (int d = 0; d < 4; ++d) {
            ur[d] = pk2(Wih[h * FAN + D_IN + k0 + 2 * d], Wih[h * FAN + D_IN + k0 + 2 * d + 1]);
            uc[d] = pk2(Wih[(k0 + 2 * d) * FAN + D_IN + h], Wih[(k0 + 2 * d + 1) * FAN + D_IN + h]);
            float e0 = (h < D_IN) ? Wih[(k0 + 2 * d) * FAN + h] : 0.0f;
            float e1 = (h < D_IN) ? Wih[(k0 + 2 * d + 1) * FAN + h] : 0.0f;
            ux[d] = pk2(e0, e1);
        }
        uint4v v;
        v[0] = ur[0]; v[1] = ur[1]; v[2] = ur[2]; v[3] = ur[3];
        *(uint4v*)((char*)Arow[0] + swz((unsigned)(h * 128 + k0 * 2))) = v;
        v[0] = uc[0]; v[1] = uc[1]; v[2] = uc[2]; v[3] = uc[3];
        *(uint4v*)((char*)Acol[0] + swz((unsigned)(h * 128 + k0 * 2))) = v;
        v[0] = ux[0]; v[1] = ux[1]; v[2] = ux[2]; v[3] = ux[3];
        *(uint4v*)((char*)Ccol[0] + swz((unsigned)(h * 128 + k0 * 2))) = v;
    }
    if (tid < 64) { Ub[tid] = bih[tid]; Wb[tid] = bih[tid]; }
    __syncthreads();

    int ab = 0, cb = 0;
    for (int i = 0; i < 7; ++i) {
        const bool domul = (t < 127) && ((n >> i) & 1);
        const bool dosq  = (i < 6);
        const char* Lr = (const char*)Arow[ab];
        f32x4 accM[2], accS[2];
#pragma unroll
        for (int e = 0; e < 2; ++e) {
            const int tt = wid * 2 + e, r = tt >> 2, c = tt & 3;
            FragU a0, a1;
            a0.u4 = *(const uint4v*)(Lr + swz((unsigned)((16 * r + st) * 128 + q * 16)));
            a1.u4 = *(const uint4v*)(Lr + swz((unsigned)((16 * r + st) * 128 + 64 + q * 16)));
            if (domul) {
                FragU b0, b1;
                b0.u4 = *(const uint4v*)((const char*)Ccol[cb] + swz((unsigned)((16 * c + st) * 128 + q * 16)));
                b1.u4 = *(const uint4v*)((const char*)Ccol[cb] + swz((unsigned)((16 * c + st) * 128 + 64 + q * 16)));
                f32x4 z = {0.f, 0.f, 0.f, 0.f};
                accM[e] = MFMA(a0.s8, b0.s8, z);
                accM[e] = MFMA(a1.s8, b1.s8, accM[e]);
            }
            if (dosq) {
                FragU b0, b1;
                b0.u4 = *(const uint4v*)((const char*)Acol[ab] + swz((unsigned)((16 * c + st) * 128 + q * 16)));
                b1.u4 = *(const uint4v*)((const char*)Acol[ab] + swz((unsigned)((16 * c + st) * 128 + 64 + q * 16)));
                f32x4 z = {0.f, 0.f, 0.f, 0.f};
                accS[e] = MFMA(a0.s8, b0.s8, z);
                accS[e] = MFMA(a1.s8, b1.s8, accS[e]);
            }
        }
        if (t == 127) {
            // matvec partials with S_i: u' = u + S u ; w' = S w
            const int h = tid >> 3, p = tid & 7;
            FragU sr;
            sr.u4 = *(const uint4v*)(Lr + swz((unsigned)(h * 128 + p * 16)));
            float su = 0.0f, sw = 0.0f;
#pragma unroll
            for (int d2 = 0; d2 < 4; ++d2) {
                float e0 = bf2f((unsigned short)(sr.u[d2] & 0xFFFFu));
                float e1 = bf2f((unsigned short)(sr.u[d2] >> 16));
                su += e0 * Ub[8 * p + 2 * d2] + e1 * Ub[8 * p + 2 * d2 + 1];
                sw += e0 * Wb[8 * p + 2 * d2] + e1 * Wb[8 * p + 2 * d2 + 1];
            }
            Ptu[h][p] = su; Ptw[h][p] = sw;
        }
        if (domul) {
#pragma unroll
            for (int e = 0; e < 2; ++e) {
                const int tt = wid * 2 + e, r = tt >> 2, c = tt & 3;
                uint2v w; w[0] = pk2(accM[e][0], accM[e][1]); w[1] = pk2(accM[e][2], accM[e][3]);
                *(uint2v*)((char*)Ccol[cb ^ 1] + swz((unsigned)((16 * c + st) * 128 + (16 * r + 4 * q) * 2))) = w;
            }
        }
        if (dosq) {
#pragma unroll
            for (int e = 0; e < 2; ++e) {
                const int tt = wid * 2 + e, r = tt >> 2, c = tt & 3;
                uint2v w; w[0] = pk2(accS[e][0], accS[e][1]); w[1] = pk2(accS[e][2], accS[e][3]);
                *(uint2v*)((char*)Acol[ab ^ 1] + swz((unsigned)((16 * c + st) * 128 + (16 * r + 4 * q) * 2))) = w;
#pragma unroll
                for (int j = 0; j < 4; ++j)
                    *(unsigned short*)((char*)Arow[ab ^ 1]
                        + swz((unsigned)((16 * r + 4 * q + j) * 128 + (16 * c + st) * 2))) = f2bf(accS[e][j]);
            }
        }
        __syncthreads();
        if (t == 127) {
            if (tid < 64) {
                float su = Ub[tid], sw = 0.0f;
#pragma unroll
                for (int p = 0; p < 8; ++p) { su += Ptu[tid][p]; sw += Ptw[tid][p]; }
                Ub[tid] = su;   // u_{i+1}
                Wb[tid] = sw;   // w_{i+1}
            }
            __syncthreads();
        }
        if (domul) cb ^= 1;
        if (dosq)  ab ^= 1;
    }

    if (t < 127) {
        for (int idx = tid; idx < 64 * D_IN; idx += 512) {
            int h = idx / D_IN, c = idx - h * D_IN;
            G[(size_t)h * GK + 57 * t + c] =
                *(const unsigned short*)((const char*)Ccol[cb] + swz((unsigned)(c * 128 + h * 2)));
        }
    } else {
        if (tid < 64) Sb[tid] = Ub[tid] - Wb[tid];   // sum_{j<=126} W^j b = u_7 - W^127 b
        for (int idx = tid; idx < 64 * (GK - KTOT); idx += 512) {
            int h = idx / (GK - KTOT), c = idx % (GK - KTOT);
            G[(size_t)h * GK + KTOT + c] = 0;
        }
    }
}

// ===== main: C[hid][seq] = G * x  (K = 7296, 8 waves), + epilogue (unchanged from R8) =====
__global__ __launch_bounds__(512, 1) void rnn_scan_main(
    const float* __restrict__ x,
    const float* __restrict__ Wih,
    const float* __restrict__ bih,
    const float* __restrict__ Wio,
    const float* __restrict__ bio,
    const char*  __restrict__ wsb,
    float* __restrict__ out,
    int B)
{
    const unsigned short* G = (const unsigned short*)wsb;
    const float* Sb = (const float*)(wsb + GBYTES);
    const int tid  = threadIdx.x;
    const int wid  = tid >> 6, lane = tid & 63;
    const int st   = lane & 15, q = lane >> 4;
    const int seq0 = blockIdx.x * 16;

    __shared__ float Red[8][1024];
    __shared__ float Hp[16][68];
    __shared__ float Lg[16][8];
    __shared__ int   Tl[16];
    __shared__ unsigned char Mb[16][32];
    __shared__ unsigned Mm[16][4];

    const bool fullblk = (seq0 + 16 <= B);
    int seqc = seq0 + st; if (seqc >= B) seqc = B - 1;
    const float* xs = x + (size_t)seqc * GK;

    {
        int s = tid & 15, g = tid >> 4;
        int sc = seq0 + s; if (sc >= B) sc = B - 1;
        const float* xr = x + (size_t)sc * GK;
        unsigned v = 0;
#pragma unroll
        for (int i = 0; i < 4; ++i)
            v |= ((xr[(size_t)(4 * g + i) * D_IN] != -1.0f) ? 1u : 0u) << i;
        Mb[s][g] = (unsigned char)v;
    }
    __syncthreads();
    int myAllv = 1;
    if (tid < 16) {
        unsigned mk[4] = {0, 0, 0, 0};
        for (int b = 0; b < 32; ++b)
            mk[b >> 3] |= ((unsigned)Mb[tid][b]) << ((b & 7) * 4);
        Mm[tid][0] = mk[0]; Mm[tid][1] = mk[1]; Mm[tid][2] = mk[2]; Mm[tid][3] = mk[3];
        myAllv = ((mk[0] & mk[1] & mk[2] & mk[3]) == 0xFFFFFFFFu) ? 1 : 0;
        int tl;
        if (mk[3])      tl = 127 - __builtin_clz(mk[3]);
        else if (mk[2]) tl =  95 - __builtin_clz(mk[2]);
        else if (mk[1]) tl =  63 - __builtin_clz(mk[1]);
        else if (mk[0]) tl =  31 - __builtin_clz(mk[0]);
        else            tl = -1;
        Tl[tid] = tl;
    }
    const int blockFast = __syncthreads_and(myAllv) && fullblk;

    int nch, kw;
    if (wid < 4) { nch = 29; kw = 928 * wid; }
    else         { nch = 28; kw = 3712 + 896 * (wid - 4); }

    f32x4 acc0 = {0,0,0,0}, acc1 = {0,0,0,0}, acc2 = {0,0,0,0}, acc3 = {0,0,0,0};
    const unsigned short* g0 = G + (size_t)(st)      * GK;
    const unsigned short* g1 = G + (size_t)(16 + st) * GK;
    const unsigned short* g2 = G + (size_t)(32 + st) * GK;
    const unsigned short* g3 = G + (size_t)(48 + st) * GK;

#pragma unroll 2
    for (int c = 0; c < nch; ++c) {
        int k0 = kw + 32 * c + 8 * q;
        f32x4 xa = *(const f32x4*)(xs + k0);
        f32x4 xb = *(const f32x4*)(xs + k0 + 4);
        FragU bx;
        bx.u[0] = pk2(xa[0], xa[1]); bx.u[1] = pk2(xa[2], xa[3]);
        bx.u[2] = pk2(xb[0], xb[1]); bx.u[3] = pk2(xb[2], xb[3]);
        FragU a0, a1, a2, a3;
        a0.u4 = *(const uint4v*)(g0 + k0);
        a1.u4 = *(const uint4v*)(g1 + k0);
        a2.u4 = *(const uint4v*)(g2 + k0);
        a3.u4 = *(const uint4v*)(g3 + k0);
        acc0 = MFMA(a0.s8, bx.s8, acc0);
        acc1 = MFMA(a1.s8, bx.s8, acc1);
        acc2 = MFMA(a2.s8, bx.s8, acc2);
        acc3 = MFMA(a3.s8, bx.s8, acc3);
    }
    {
        const f32x4 av[4] = { acc0, acc1, acc2, acc3 };
#pragma unroll
        for (int n = 0; n < 4; ++n)
#pragma unroll
            for (int jj = 0; jj < 4; ++jj)
                Red[wid][(16 * n + 4 * q + jj) * 16 + st] = av[n][jj];
    }
    __syncthreads();
    for (int idx = tid; idx < 1024; idx += 512) {
        float s = 0;
#pragma unroll
        for (int w = 0; w < 8; ++w) s += Red[w][idx];
        int hid = idx >> 4, sq = idx & 15;
        Hp[sq][hid] = s + Sb[hid];
    }
    __syncthreads();

    if (!blockFast) {
        if (wid == 0) {
            unsigned short* HsS = (unsigned short*)&Red[0][0];
            char* HsB = (char*)HsS;
            { uint4v z = {0,0,0,0};
              *(uint4v*)(HsB + lane * 32) = z; *(uint4v*)(HsB + lane * 32 + 16) = z; }
            short8 wxf[4][2], whf[4][2]; f32x4 biasv[4];
#pragma unroll
            for (int n = 0; n < 4; ++n) {
                const float* wr_ = Wih + (size_t)(16 * n + st) * FAN;
                wxf[n][0] = wfragX(wr_, q * 8);
                wxf[n][1] = wfragX(wr_, 32 + q * 8);
                whf[n][0] = wfragH(wr_ + D_IN, q * 8);
                whf[n][1] = wfragH(wr_ + D_IN, 32 + q * 8);
#pragma unroll
                for (int jj = 0; jj < 4; ++jj) biasv[n][jj] = bih[16 * n + 4 * q + jj];
            }
            const unsigned rb0 = (unsigned)(128 * st + 16 * q);
            const unsigned rb1 = (unsigned)(128 * st + 64 + 16 * q);
            unsigned wb[4];
#pragma unroll
            for (int n = 0; n < 4; ++n) wb[n] = (unsigned)(128 * st + 32 * n + 8 * q);
            unsigned mkw[4] = { Mm[st][0], Mm[st][1], Mm[st][2], Mm[st][3] };
            f32x4 hcur[4], hpre[4];
#pragma unroll
            for (int n = 0; n < 4; ++n) { hcur[n] = (f32x4){0,0,0,0}; hpre[n] = (f32x4){0,0,0,0}; }
#pragma unroll 1
            for (int t = 0; t < T_STEPS; ++t) {
                XR r; loadx(r, xs, t, q);
                FragU bh0, bh1;
                bh0.u4 = *(const uint4v*)(HsB + rb0);
                bh1.u4 = *(const uint4v*)(HsB + rb1);
                short8 bx0 = xfrag(r.a), bx1 = xfrag(r.b);
                f32x4 acc[4];
#pragma unroll
                for (int n = 0; n < 4; ++n) {
                    f32x4 cc2 = biasv[n];
                    cc2 = MFMA(wxf[n][0], bx0, cc2);
                    cc2 = MFMA(wxf[n][1], bx1, cc2);
                    cc2 = MFMA(whf[n][0], bh0.s8, cc2);
                    cc2 = MFMA(whf[n][1], bh1.s8, cc2);
                    acc[n] = cc2;
                }
                bool v = ((mkw[t >> 5] >> (t & 31)) & 1u) != 0;
#pragma unroll
                for (int n = 0; n < 4; ++n)
#pragma unroll
                    for (int jj = 0; jj < 4; ++jj) {
                        float o = hcur[n][jj];
                        hpre[n][jj] = v ? o : hpre[n][jj];
                        hcur[n][jj] = v ? acc[n][jj] : o;
                    }
#pragma unroll
                for (int n = 0; n < 4; ++n) {
                    uint2v w2;
                    w2[0] = pk2(hcur[n][0], hcur[n][1]);
                    w2[1] = pk2(hcur[n][2], hcur[n][3]);
                    *(uint2v*)(HsB + wb[n]) = w2;
                }
                DS_FENCE();
            }
#pragma unroll
            for (int n = 0; n < 4; ++n)
                *(f32x4*)&Hp[st][16 * n + 4 * q] = hpre[n];
        }
        __syncthreads();
    }

    if (tid < 64) {
        int s = tid >> 2, p = tid & 3;
        int seq = seq0 + s;
        int t_l = Tl[s];
        float lgo0 = 0.0f, lgo1 = 0.0f;
        if (seq < B && t_l >= 0) {
            const float* xr = x + (size_t)seq * GK + (size_t)t_l * D_IN;
            {
                const float* wo = Wio + p * FAN;
                float a = bio[p];
                for (int k = 0; k < D_IN; ++k) a += xr[k] * wo[k];
                for (int k = 0; k < HDIM; ++k) a += Hp[s][k] * wo[D_IN + k];
                lgo0 = a;
            }
            if (p < 3) {
                const float* wo = Wio + (p + 4) * FAN;
                float a = bio[p + 4];
                for (int k = 0; k < D_IN; ++k) a += xr[k] * wo[k];
                for (int k = 0; k < HDIM; ++k) a += Hp[s][k] * wo[D_IN + k];
                lgo1 = a;
            }
        }
        Lg[s][p] = lgo0;
        if (p < 3) Lg[s][p + 4] = lgo1;
    }
    __syncthreads();
    if (tid < 16) {
        int s = tid, seq = seq0 + s;
        if (seq < B) {
            float* op = out + (size_t)seq * ODIM;
            if (Tl[s] < 0) {
#pragma unroll
                for (int o = 0; o < ODIM; ++o) op[o] = 0.0f;
            } else {
                float m = Lg[s][0];
#pragma unroll
                for (int o = 1; o < ODIM; ++o) m = fmaxf(m, Lg[s][o]);
                float sum = 0.0f;
#pragma unroll
                for (int o = 0; o < ODIM; ++o) sum += expf(Lg[s][o] - m);
                float lse = m + logf(sum);
#pragma unroll
                for (int o = 0; o < ODIM; ++o) op[o] = Lg[s][o] - lse;
            }
        }
    }
}

extern "C" void kernel_launch(void* const* d_in, const int* in_sizes, int n_in,
                              void* d_out, int out_size, void* d_ws, size_t ws_size,
                              hipStream_t stream)
{
    const float* x     = (const float*)d_in[0];
    const float* W_i2h = (const float*)d_in[1];
    const float* b_i2h = (const float*)d_in[2];
    const float* W_i2o = (const float*)d_in[3];
    const float* b_i2o = (const float*)d_in[4];
    float* out = (float*)d_out;
    char*  wsb = (char*)d_ws;

    const int B = in_sizes[0] / (T_STEPS * D_IN);
    const int nblk = (B + 15) / 16;

    hipLaunchKernelGGL(rnn_prep,      dim3(128),  dim3(512), 0, stream, W_i2h, b_i2h, wsb);
    hipLaunchKernelGGL(rnn_scan_main, dim3(nblk), dim3(512), 0, stream,
                       x, W_i2h, b_i2h, W_i2o, b_i2o, (const char*)wsb, out, B);
}

// Round 10
// 58.654 us; speedup vs baseline: 3.9555x; 1.1154x over previous
//
#include <hip/hip_runtime.h>
#include <cstddef>

#define T_STEPS 128
#define D_IN    57
#define HDIM    64
#define ODIM    7
#define FAN     121
#define GK      7296          // floats per x row == bf16 cols per G row (128*57)
#define KTOT    7239          // 127*57 real columns
#define GBYTES  ((size_t)HDIM * GK * 2)

typedef __attribute__((ext_vector_type(8))) short    short8;
typedef __attribute__((ext_vector_type(4))) float    f32x4;
typedef __attribute__((ext_vector_type(4))) unsigned uint4v;
typedef __attribute__((ext_vector_type(2))) unsigned uint2v;

#define MFMA(a,b,c) __builtin_amdgcn_mfma_f32_16x16x32_bf16((a),(b),(c),0,0,0)
#define DS_FENCE()  __builtin_amdgcn_sched_barrier(0x7F)

union FragU { short8 s8; unsigned u[4]; uint4v u4; };

__device__ inline unsigned short f2bf(float f) {
    __bf16 h = (__bf16)f;
    return __builtin_bit_cast(unsigned short, h);
}
__device__ inline float bf2f(unsigned short u) {
    return __builtin_bit_cast(float, (unsigned)u << 16);
}
__device__ inline unsigned pk2(float lo, float hi) {
    return ((unsigned)f2bf(hi) << 16) | (unsigned)f2bf(lo);
}
// Involutive swizzle for 128B-row LDS tiles (verified R3-R6)
__device__ inline unsigned swz(unsigned b) {
    return b ^ (((b >> 7) & 7u) << 4);
}

__device__ inline short8 wfragX(const float* Wr, int kbase) {
    FragU f;
#pragma unroll
    for (int d = 0; d < 4; ++d) {
        int k0 = kbase + 2 * d, k1 = k0 + 1;
        float a = (k0 < D_IN) ? Wr[k0] : 0.0f;
        float b = (k1 < D_IN) ? Wr[k1] : 0.0f;
        f.u[d] = pk2(a, b);
    }
    return f.s8;
}
__device__ inline short8 wfragH(const float* Wr, int kbase) {
    FragU f;
#pragma unroll
    for (int d = 0; d < 4; ++d) { int k0 = kbase + 2 * d; f.u[d] = pk2(Wr[k0], Wr[k0 + 1]); }
    return f.s8;
}
__device__ inline short8 xfrag(const float* r) {
    FragU f;
#pragma unroll
    for (int d = 0; d < 4; ++d) f.u[d] = pk2(r[2 * d], r[2 * d + 1]);
    return f.s8;
}

struct XR { float a[8]; float b[8]; };
__device__ inline void loadx(XR& r, const float* xrow, int t, int q) {
    const float* p = xrow + t * D_IN;
#pragma unroll
    for (int i = 0; i < 8; ++i) r.a[i] = p[q * 8 + i];
    if (q == 3) {
        r.b[0] = p[56];
#pragma unroll
        for (int i = 1; i < 8; ++i) r.b[i] = 0.0f;
    } else {
#pragma unroll
        for (int i = 0; i < 8; ++i) r.b[i] = p[32 + q * 8 + i];
    }
}

// ===== prep (128 blocks, fully parallel, MFMA in swizzled bf16 LDS) — unchanged from R9 =====
__global__ __launch_bounds__(512, 1) void rnn_prep(
    const float* __restrict__ Wih, const float* __restrict__ bih, char* __restrict__ wsb)
{
    unsigned short* G  = (unsigned short*)wsb;
    float*          Sb = (float*)(wsb + GBYTES);
    const int t    = blockIdx.x;          // 0..127
    const int n    = 126 - t;             // t==127 -> n<0: no cur-mults
    const int tid  = threadIdx.x;
    const int lane = tid & 63, wid = tid >> 6;
    const int st   = lane & 15, q = lane >> 4;

    __shared__ __align__(16) unsigned short Arow[2][64][64];
    __shared__ __align__(16) unsigned short Acol[2][64][64];
    __shared__ __align__(16) unsigned short Ccol[2][64][64];
    __shared__ float Ub[64], Wb[64], Ptu[64][8], Ptw[64][8];

    {
        const int h  = tid & 63;
        const int k0 = (tid >> 6) * 8;
        unsigned ur[4], uc[4], ux[4];
#pragma unroll
        for (int d = 0; d < 4; ++d) {
            ur[d] = pk2(Wih[h * FAN + D_IN + k0 + 2 * d], Wih[h * FAN + D_IN + k0 + 2 * d + 1]);
            uc[d] = pk2(Wih[(k0 + 2 * d) * FAN + D_IN + h], Wih[(k0 + 2 * d + 1) * FAN + D_IN + h]);
            float e0 = (h < D_IN) ? Wih[(k0 + 2 * d) * FAN + h] : 0.0f;
            float e1 = (h < D_IN) ? Wih[(k0 + 2 * d + 1) * FAN + h] : 0.0f;
            ux[d] = pk2(e0, e1);
        }
        uint4v v;
        v[0] = ur[0]; v[1] = ur[1]; v[2] = ur[2]; v[3] = ur[3];
        *(uint4v*)((char*)Arow[0] + swz((unsigned)(h * 128 + k0 * 2))) = v;
        v[0] = uc[0]; v[1] = uc[1]; v[2] = uc[2]; v[3] = uc[3];
        *(uint4v*)((char*)Acol[0] + swz((unsigned)(h * 128 + k0 * 2))) = v;
        v[0] = ux[0]; v[1] = ux[1]; v[2] = ux[2]; v[3] = ux[3];
        *(uint4v*)((char*)Ccol[0] + swz((unsigned)(h * 128 + k0 * 2))) = v;
    }
    if (tid < 64) { Ub[tid] = bih[tid]; Wb[tid] = bih[tid]; }
    __syncthreads();

    int ab = 0, cb = 0;
    for (int i = 0; i < 7; ++i) {
        const bool domul = (t < 127) && ((n >> i) & 1);
        const bool dosq  = (i < 6);
        const char* Lr = (const char*)Arow[ab];
        f32x4 accM[2], accS[2];
#pragma unroll
        for (int e = 0; e < 2; ++e) {
            const int tt = wid * 2 + e, r = tt >> 2, c = tt & 3;
            FragU a0, a1;
            a0.u4 = *(const uint4v*)(Lr + swz((unsigned)((16 * r + st) * 128 + q * 16)));
            a1.u4 = *(const uint4v*)(Lr + swz((unsigned)((16 * r + st) * 128 + 64 + q * 16)));
            if (domul) {
                FragU b0, b1;
                b0.u4 = *(const uint4v*)((const char*)Ccol[cb] + swz((unsigned)((16 * c + st) * 128 + q * 16)));
                b1.u4 = *(const uint4v*)((const char*)Ccol[cb] + swz((unsigned)((16 * c + st) * 128 + 64 + q * 16)));
                f32x4 z = {0.f, 0.f, 0.f, 0.f};
                accM[e] = MFMA(a0.s8, b0.s8, z);
                accM[e] = MFMA(a1.s8, b1.s8, accM[e]);
            }
            if (dosq) {
                FragU b0, b1;
                b0.u4 = *(const uint4v*)((const char*)Acol[ab] + swz((unsigned)((16 * c + st) * 128 + q * 16)));
                b1.u4 = *(const uint4v*)((const char*)Acol[ab] + swz((unsigned)((16 * c + st) * 128 + 64 + q * 16)));
                f32x4 z = {0.f, 0.f, 0.f, 0.f};
                accS[e] = MFMA(a0.s8, b0.s8, z);
                accS[e] = MFMA(a1.s8, b1.s8, accS[e]);
            }
        }
        if (t == 127) {
            const int h = tid >> 3, p = tid & 7;
            FragU sr;
            sr.u4 = *(const uint4v*)(Lr + swz((unsigned)(h * 128 + p * 16)));
            float su = 0.0f, sw = 0.0f;
#pragma unroll
            for (int d2 = 0; d2 < 4; ++d2) {
                float e0 = bf2f((unsigned short)(sr.u[d2] & 0xFFFFu));
                float e1 = bf2f((unsigned short)(sr.u[d2] >> 16));
                su += e0 * Ub[8 * p + 2 * d2] + e1 * Ub[8 * p + 2 * d2 + 1];
                sw += e0 * Wb[8 * p + 2 * d2] + e1 * Wb[8 * p + 2 * d2 + 1];
            }
            Ptu[h][p] = su; Ptw[h][p] = sw;
        }
        if (domul) {
#pragma unroll
            for (int e = 0; e < 2; ++e) {
                const int tt = wid * 2 + e, r = tt >> 2, c = tt & 3;
                uint2v w; w[0] = pk2(accM[e][0], accM[e][1]); w[1] = pk2(accM[e][2], accM[e][3]);
                *(uint2v*)((char*)Ccol[cb ^ 1] + swz((unsigned)((16 * c + st) * 128 + (16 * r + 4 * q) * 2))) = w;
            }
        }
        if (dosq) {
#pragma unroll
            for (int e = 0; e < 2; ++e) {
                const int tt = wid * 2 + e, r = tt >> 2, c = tt & 3;
                uint2v w; w[0] = pk2(accS[e][0], accS[e][1]); w[1] = pk2(accS[e][2], accS[e][3]);
                *(uint2v*)((char*)Acol[ab ^ 1] + swz((unsigned)((16 * c + st) * 128 + (16 * r + 4 * q) * 2))) = w;
#pragma unroll
                for (int j = 0; j < 4; ++j)
                    *(unsigned short*)((char*)Arow[ab ^ 1]
                        + swz((unsigned)((16 * r + 4 * q + j) * 128 + (16 * c + st) * 2))) = f2bf(accS[e][j]);
            }
        }
        __syncthreads();
        if (t == 127) {
            if (tid < 64) {
                float su = Ub[tid], sw = 0.0f;
#pragma unroll
                for (int p = 0; p < 8; ++p) { su += Ptu[tid][p]; sw += Ptw[tid][p]; }
                Ub[tid] = su;
                Wb[tid] = sw;
            }
            __syncthreads();
        }
        if (domul) cb ^= 1;
        if (dosq)  ab ^= 1;
    }

    if (t < 127) {
        for (int idx = tid; idx < 64 * D_IN; idx += 512) {
            int h = idx / D_IN, c = idx - h * D_IN;
            G[(size_t)h * GK + 57 * t + c] =
                *(const unsigned short*)((const char*)Ccol[cb] + swz((unsigned)(c * 128 + h * 2)));
        }
    } else {
        if (tid < 64) Sb[tid] = Ub[tid] - Wb[tid];
        for (int idx = tid; idx < 64 * (GK - KTOT); idx += 512) {
            int h = idx / (GK - KTOT), c = idx % (GK - KTOT);
            G[(size_t)h * GK + KTOT + c] = 0;
        }
    }
}

// ===== main: C[hid][seq] = G * x  (K = 7296, 16 waves, fused validity check) =====
__global__ __launch_bounds__(1024, 1) void rnn_scan_main(
    const float* __restrict__ x,
    const float* __restrict__ Wih,
    const float* __restrict__ bih,
    const float* __restrict__ Wio,
    const float* __restrict__ bio,
    const char*  __restrict__ wsb,
    float* __restrict__ out,
    int B)
{
    const unsigned short* G = (const unsigned short*)wsb;
    const float* Sb = (const float*)(wsb + GBYTES);
    const int tid  = threadIdx.x;
    const int wid  = tid >> 6, lane = tid & 63;
    const int st   = lane & 15, q = lane >> 4;
    const int seq0 = blockIdx.x * 16;

    __shared__ float Red[16][1024];      // 64 KB
    __shared__ float Hp[16][68];
    __shared__ float Lg[16][8];
    __shared__ int   Tl[16];
    __shared__ int   FlgL[16];
    __shared__ unsigned char Mb[16][32];
    __shared__ unsigned Mm[16][4];

    if (tid < 16) FlgL[tid] = 0;
    const bool fullblk = (seq0 + 16 <= B);
    int seqc = seq0 + st; if (seqc >= B) seqc = B - 1;
    const float* xs = x + (size_t)seqc * GK;
    __syncthreads();   // FlgL init visible before any atomicOr

    // K split: 228 chunks of 32 floats over 16 waves (4x15 + 12x14)
    int nch, kw;
    if (wid < 4) { nch = 15; kw = 480 * wid; }
    else         { nch = 14; kw = 1920 + 448 * (wid - 4); }

    f32x4 acc0 = {0,0,0,0}, acc1 = {0,0,0,0}, acc2 = {0,0,0,0}, acc3 = {0,0,0,0};
    const unsigned short* g0 = G + (size_t)(st)      * GK;
    const unsigned short* g1 = G + (size_t)(16 + st) * GK;
    const unsigned short* g2 = G + (size_t)(32 + st) * GK;
    const unsigned short* g3 = G + (size_t)(48 + st) * GK;

    int ms = kw % 57;          // chunk-start mod 57 (incrementally maintained)
    bool flag = false;         // this lane observed an invalid x[t][0]

#pragma unroll 2
    for (int c = 0; c < nch; ++c) {
        int k0 = kw + 32 * c + 8 * q;
        f32x4 xa = *(const f32x4*)(xs + k0);
        f32x4 xb = *(const f32x4*)(xs + k0 + 4);
        FragU bx;
        bx.u[0] = pk2(xa[0], xa[1]); bx.u[1] = pk2(xa[2], xa[3]);
        bx.u[2] = pk2(xb[0], xb[1]); bx.u[3] = pk2(xb[2], xb[3]);
        FragU a0, a1, a2, a3;
        a0.u4 = *(const uint4v*)(g0 + k0);
        a1.u4 = *(const uint4v*)(g1 + k0);
        a2.u4 = *(const uint4v*)(g2 + k0);
        a3.u4 = *(const uint4v*)(g3 + k0);
        acc0 = MFMA(a0.s8, bx.s8, acc0);
        acc1 = MFMA(a1.s8, bx.s8, acc1);
        acc2 = MFMA(a2.s8, bx.s8, acc2);
        acc3 = MFMA(a3.s8, bx.s8, acc3);
        // fused validity: position o = offset of (k % 57 == 0) within this 32-chunk
        {
            int o  = (ms == 0) ? 0 : (57 - ms);
            int io = o - 8 * q;
            if (io >= 0 && io < 8) {
                float v = (io == 0) ? xa[0] : (io == 1) ? xa[1] : (io == 2) ? xa[2]
                        : (io == 3) ? xa[3] : (io == 4) ? xb[0] : (io == 5) ? xb[1]
                        : (io == 6) ? xb[2] : xb[3];
                flag |= (v == -1.0f);
            }
            ms += 32; if (ms >= 57) ms -= 57;
        }
    }
    if (flag) atomicOr(&FlgL[st], 1);
    {
        const f32x4 av[4] = { acc0, acc1, acc2, acc3 };
#pragma unroll
        for (int n = 0; n < 4; ++n)
#pragma unroll
            for (int jj = 0; jj < 4; ++jj)
                Red[wid][(16 * n + 4 * q + jj) * 16 + st] = av[n][jj];
    }
    __syncthreads();

    int anyBad = 0;
#pragma unroll
    for (int s2 = 0; s2 < 16; ++s2) anyBad |= FlgL[s2];
    const bool blockFast = fullblk && (anyBad == 0);

    {   // reduce 16 wave-partials, add bias-sum
        int idx = tid;                      // exactly one element per thread
        float s = 0;
#pragma unroll
        for (int w = 0; w < 16; ++w) s += Red[w][idx];
        int hid = idx >> 4, sq = idx & 15;
        Hp[sq][hid] = s + Sb[hid];
    }
    if (tid < 16) Tl[tid] = 127;            // fast-path default (all valid)
    __syncthreads();

    if (!blockFast) {
        // full mask scan (slow path only)
        if (tid < 512) {
            int s = tid & 15, g = tid >> 4;
            int sc = seq0 + s; if (sc >= B) sc = B - 1;
            const float* xr = x + (size_t)sc * GK;
            unsigned v = 0;
#pragma unroll
            for (int i = 0; i < 4; ++i)
                v |= ((xr[(size_t)(4 * g + i) * D_IN] != -1.0f) ? 1u : 0u) << i;
            Mb[s][g] = (unsigned char)v;
        }
        __syncthreads();
        if (tid < 16) {
            unsigned mk[4] = {0, 0, 0, 0};
            for (int b = 0; b < 32; ++b)
                mk[b >> 3] |= ((unsigned)Mb[tid][b]) << ((b & 7) * 4);
            Mm[tid][0] = mk[0]; Mm[tid][1] = mk[1]; Mm[tid][2] = mk[2]; Mm[tid][3] = mk[3];
            int tl;
            if (mk[3])      tl = 127 - __builtin_clz(mk[3]);
            else if (mk[2]) tl =  95 - __builtin_clz(mk[2]);
            else if (mk[1]) tl =  63 - __builtin_clz(mk[1]);
            else if (mk[0]) tl =  31 - __builtin_clz(mk[0]);
            else            tl = -1;
            Tl[tid] = tl;
        }
        __syncthreads();
        if (wid == 0) {
            unsigned short* HsS = (unsigned short*)&Red[0][0];
            char* HsB = (char*)HsS;
            { uint4v z = {0,0,0,0};
              *(uint4v*)(HsB + lane * 32) = z; *(uint4v*)(HsB + lane * 32 + 16) = z; }
            short8 wxf[4][2], whf[4][2]; f32x4 biasv[4];
#pragma unroll
            for (int n = 0; n < 4; ++n) {
                const float* wr_ = Wih + (size_t)(16 * n + st) * FAN;
                wxf[n][0] = wfragX(wr_, q * 8);
                wxf[n][1] = wfragX(wr_, 32 + q * 8);
                whf[n][0] = wfragH(wr_ + D_IN, q * 8);
                whf[n][1] = wfragH(wr_ + D_IN, 32 + q * 8);
#pragma unroll
                for (int jj = 0; jj < 4; ++jj) biasv[n][jj] = bih[16 * n + 4 * q + jj];
            }
            const unsigned rb0 = (unsigned)(128 * st + 16 * q);
            const unsigned rb1 = (unsigned)(128 * st + 64 + 16 * q);
            unsigned wb[4];
#pragma unroll
            for (int n = 0; n < 4; ++n) wb[n] = (unsigned)(128 * st + 32 * n + 8 * q);
            unsigned mkw[4] = { Mm[st][0], Mm[st][1], Mm[st][2], Mm[st][3] };
            f32x4 hcur[4], hpre[4];
#pragma unroll
            for (int n = 0; n < 4; ++n) { hcur[n] = (f32x4){0,0,0,0}; hpre[n] = (f32x4){0,0,0,0}; }
#pragma unroll 1
            for (int t = 0; t < T_STEPS; ++t) {
                XR r; loadx(r, xs, t, q);
                FragU bh0, bh1;
                bh0.u4 = *(const uint4v*)(HsB + rb0);
                bh1.u4 = *(const uint4v*)(HsB + rb1);
                short8 bx0 = xfrag(r.a), bx1 = xfrag(r.b);
                f32x4 acc[4];
#pragma unroll
                for (int n = 0; n < 4; ++n) {
                    f32x4 cc2 = biasv[n];
                    cc2 = MFMA(wxf[n][0], bx0, cc2);
                    cc2 = MFMA(wxf[n][1], bx1, cc2);
                    cc2 = MFMA(whf[n][0], bh0.s8, cc2);
                    cc2 = MFMA(whf[n][1], bh1.s8, cc2);
                    acc[n] = cc2;
                }
                bool v = ((mkw[t >> 5] >> (t & 31)) & 1u) != 0;
#pragma unroll
                for (int n = 0; n < 4; ++n)
#pragma unroll
                    for (int jj = 0; jj < 4; ++jj) {
                        float o = hcur[n][jj];
                        hpre[n][jj] = v ? o : hpre[n][jj];
                        hcur[n][jj] = v ? acc[n][jj] : o;
                    }
#pragma unroll
                for (int n = 0; n < 4; ++n) {
                    uint2v w2;
                    w2[0] = pk2(hcur[n][0], hcur[n][1]);
                    w2[1] = pk2(hcur[n][2], hcur[n][3]);
                    *(uint2v*)(HsB + wb[n]) = w2;
                }
                DS_FENCE();
            }
#pragma unroll
            for (int n = 0; n < 4; ++n)
                *(f32x4*)&Hp[st][16 * n + 4 * q] = hpre[n];
        }
        __syncthreads();
    }

    if (tid < 64) {
        int s = tid >> 2, p = tid & 3;
        int seq = seq0 + s;
        int t_l = Tl[s];
        float lgo0 = 0.0f, lgo1 = 0.0f;
        if (seq < B && t_l >= 0) {
            const float* xr = x + (size_t)seq * GK + (size_t)t_l * D_IN;
            {
                const float* wo = Wio + p * FAN;
                float a = bio[p];
                for (int k = 0; k < D_IN; ++k) a += xr[k] * wo[k];
                for (int k = 0; k < HDIM; ++k) a += Hp[s][k] * wo[D_IN + k];
                lgo0 = a;
            }
            if (p < 3) {
                const float* wo = Wio + (p + 4) * FAN;
                float a = bio[p + 4];
                for (int k = 0; k < D_IN; ++k) a += xr[k] * wo[k];
                for (int k = 0; k < HDIM; ++k) a += Hp[s][k] * wo[D_IN + k];
                lgo1 = a;
            }
        }
        Lg[s][p] = lgo0;
        if (p < 3) Lg[s][p + 4] = lgo1;
    }
    __syncthreads();
    if (tid < 16) {
        int s = tid, seq = seq0 + s;
        if (seq < B) {
            float* op = out + (size_t)seq * ODIM;
            if (Tl[s] < 0) {
#pragma unroll
                for (int o = 0; o < ODIM; ++o) op[o] = 0.0f;
            } else {
                float m = Lg[s][0];
#pragma unroll
                for (int o = 1; o < ODIM; ++o) m = fmaxf(m, Lg[s][o]);
                float sum = 0.0f;
#pragma unroll
                for (int o = 0; o < ODIM; ++o) sum += expf(Lg[s][o] - m);
                float lse = m + logf(sum);
#pragma unroll
                for (int o = 0; o < ODIM; ++o) op[o] = Lg[s][o] - lse;
            }
        }
    }
}

extern "C" void kernel_launch(void* const* d_in, const int* in_sizes, int n_in,
                              void* d_out, int out_size, void* d_ws, size_t ws_size,
                              hipStream_t stream)
{
    const float* x     = (const float*)d_in[0];
    const float* W_i2h = (const float*)d_in[1];
    const float* b_i2h = (const float*)d_in[2];
    const float* W_i2o = (const float*)d_in[3];
    const float* b_i2o = (const float*)d_in[4];
    float* out = (float*)d_out;
    char*  wsb = (char*)d_ws;

    const int B = in_sizes[0] / (T_STEPS * D_IN);
    const int nblk = (B + 15) / 16;

    hipLaunchKernelGGL(rnn_prep,      dim3(128),  dim3(512),  0, stream, W_i2h, b_i2h, wsb);
    hipLaunchKernelGGL(rnn_scan_main, dim3(nblk), dim3(1024), 0, stream,
                       x, W_i2h, b_i2h, W_i2o, b_i2o, (const char*)wsb, out, B);
}